// Round 2
// baseline (794.617 us; speedup 1.0000x reference)
//
#include <hip/hip_runtime.h>
#include <hip/hip_bf16.h>

#define NN 20000
#define NE 320000

// ---------------- CSR construction ----------------

__global__ void zero_i32(int* __restrict__ p, int n) {
  int i = blockIdx.x * blockDim.x + threadIdx.x;
  if (i < n) p[i] = 0;
}

__global__ void count_dst(const int* __restrict__ ei, int* __restrict__ counts) {
  int e = blockIdx.x * blockDim.x + threadIdx.x;
  if (e < NE) atomicAdd(&counts[ei[NE + e]], 1);
}

// single workgroup scan: row_ptr[i+1] = inclusive(counts), cursor[i] = exclusive
__global__ void scan_counts(const int* __restrict__ counts, int* __restrict__ row_ptr,
                            int* __restrict__ cursor) {
  __shared__ int sh[1024];
  __shared__ int carry;
  int t = threadIdx.x;
  if (t == 0) { carry = 0; row_ptr[0] = 0; }
  __syncthreads();
  for (int base = 0; base < NN; base += 1024) {
    int i = base + t;
    int v = (i < NN) ? counts[i] : 0;
    sh[t] = v;
    __syncthreads();
    for (int off = 1; off < 1024; off <<= 1) {
      int add = (t >= off) ? sh[t - off] : 0;
      __syncthreads();
      sh[t] += add;
      __syncthreads();
    }
    int inc = sh[t] + carry;
    if (i < NN) { row_ptr[i + 1] = inc; cursor[i] = inc - v; }
    __syncthreads();
    if (t == 1023) carry = inc;
    __syncthreads();
  }
}

__global__ void scatter_edges(const int* __restrict__ ei, int* __restrict__ cursor,
                              int* __restrict__ perm) {
  int e = blockIdx.x * blockDim.x + threadIdx.x;
  if (e < NE) {
    int d = ei[NE + e];
    int pos = atomicAdd(&cursor[d], 1);
    perm[pos] = e;
  }
}

// ---------------- projection GEMM: C[M][NC] = A[M][K] @ W[K][NC] ----------------
// blockDim.x = NC (one column per thread), TM rows per block, A tile in LDS.

template<int K, int NC, int TM>
__global__ void gemm_tile(const float* __restrict__ A, const float* __restrict__ W,
                          float* __restrict__ C, int M) {
  __shared__ float As[TM * K];
  int n = threadIdx.x;
  int m0 = blockIdx.x * TM;
  for (int idx = n; idx < TM * K; idx += NC) {
    int m = idx / K, k = idx - m * K;
    int gm = m0 + m;
    As[idx] = (gm < M) ? A[(size_t)gm * K + k] : 0.f;
  }
  __syncthreads();
  float acc[TM];
#pragma unroll
  for (int m = 0; m < TM; ++m) acc[m] = 0.f;
  for (int k = 0; k < K; ++k) {
    float w = W[k * NC + n];
#pragma unroll
    for (int m = 0; m < TM; ++m) acc[m] += As[m * K + k] * w;
  }
#pragma unroll
  for (int m = 0; m < TM; ++m) {
    int gm = m0 + m;
    if (gm < M) C[(size_t)gm * NC + n] = acc[m];
  }
}

// ---------------- edge logits ----------------
// layer 1: wave per edge; lane l handles c=l for each of 4 heads.

__global__ void edge_logits1(const int* __restrict__ ei, const float* __restrict__ eattr,
                             const float* __restrict__ xl, const float* __restrict__ xr,
                             const float* __restrict__ We, const float* __restrict__ att,
                             float* __restrict__ logits) {
  int w = threadIdx.x >> 6, lane = threadIdx.x & 63;
  int e = blockIdx.x * 4 + w;
  if (e >= NE) return;
  int src = ei[e], dst = ei[NE + e];
  float eat[16];
#pragma unroll
  for (int k = 0; k < 16; ++k) eat[k] = eattr[e * 16 + k];
  float s[4];
#pragma unroll
  for (int h = 0; h < 4; ++h) {
    int j = h * 64 + lane;
    float v = xl[(size_t)src * 256 + j] + xr[(size_t)dst * 256 + j];
#pragma unroll
    for (int k = 0; k < 16; ++k) v += eat[k] * We[k * 256 + j];
    v = (v > 0.f) ? v : 0.2f * v;
    s[h] = att[h * 64 + lane] * v;
  }
#pragma unroll
  for (int off = 32; off > 0; off >>= 1) {
#pragma unroll
    for (int h = 0; h < 4; ++h) s[h] += __shfl_xor(s[h], off);
  }
  if (lane == 0) {
    logits[e * 4 + 0] = s[0];
    logits[e * 4 + 1] = s[1];
    logits[e * 4 + 2] = s[2];
    logits[e * 4 + 3] = s[3];
  }
}

__global__ void edge_logits2(const int* __restrict__ ei, const float* __restrict__ eattr,
                             const float* __restrict__ xl, const float* __restrict__ xr,
                             const float* __restrict__ We, const float* __restrict__ att,
                             float* __restrict__ logits) {
  int w = threadIdx.x >> 6, lane = threadIdx.x & 63;
  int e = blockIdx.x * 4 + w;
  if (e >= NE) return;
  int src = ei[e], dst = ei[NE + e];
  float v = xl[(size_t)src * 64 + lane] + xr[(size_t)dst * 64 + lane];
#pragma unroll
  for (int k = 0; k < 16; ++k) v += eattr[e * 16 + k] * We[k * 64 + lane];
  v = (v > 0.f) ? v : 0.2f * v;
  float s = att[lane] * v;
#pragma unroll
  for (int off = 32; off > 0; off >>= 1) s += __shfl_xor(s, off);
  if (lane == 0) logits[e] = s;
}

// ---------------- per-node softmax + aggregation ----------------

__global__ void aggregate1(const int* __restrict__ ei, const int* __restrict__ row_ptr,
                           const int* __restrict__ perm, const float* __restrict__ logits,
                           const float* __restrict__ xl, const float* __restrict__ bias,
                           float* __restrict__ hout) {
  int n = blockIdx.x, t = threadIdx.x, h = t >> 6;
  int beg = row_ptr[n], end = row_ptr[n + 1];
  float m = -1e30f;
  for (int i = beg; i < end; ++i) m = fmaxf(m, logits[perm[i] * 4 + h]);
  float acc = 0.f, denom = 0.f;
  for (int i = beg; i < end; ++i) {
    int e = perm[i];
    float a = __expf(logits[e * 4 + h] - m);
    denom += a;
    acc += a * xl[(size_t)ei[e] * 256 + t];
  }
  float o = (end > beg) ? (acc / denom) : 0.f;
  o += bias[t];
  o = (o > 0.f) ? o : (__expf(o) - 1.f);  // ELU (alpha=1)
  hout[(size_t)n * 256 + t] = o;
}

__global__ void aggregate2(const int* __restrict__ ei, const int* __restrict__ row_ptr,
                           const int* __restrict__ perm, const float* __restrict__ logits,
                           const float* __restrict__ xl, const float* __restrict__ bias,
                           float* __restrict__ out) {
  int n = blockIdx.x, t = threadIdx.x;
  int beg = row_ptr[n], end = row_ptr[n + 1];
  float m = -1e30f;
  for (int i = beg; i < end; ++i) m = fmaxf(m, logits[perm[i]]);
  float acc = 0.f, denom = 0.f;
  for (int i = beg; i < end; ++i) {
    int e = perm[i];
    float a = __expf(logits[e] - m);
    denom += a;
    acc += a * xl[(size_t)ei[e] * 64 + t];
  }
  float o = (end > beg) ? (acc / denom) : 0.f;
  o += bias[t];
  out[(size_t)n * 64 + t] = o;
}

// ---------------- launch ----------------

extern "C" void kernel_launch(void* const* d_in, const int* in_sizes, int n_in,
                              void* d_out, int out_size, void* d_ws, size_t ws_size,
                              hipStream_t stream) {
  const float* x    = (const float*)d_in[0];
  const int*   ei   = (const int*)  d_in[1];
  const float* eatt = (const float*)d_in[2];
  const float* Wl1  = (const float*)d_in[3];
  const float* Wr1  = (const float*)d_in[4];
  const float* We1  = (const float*)d_in[5];
  const float* att1 = (const float*)d_in[6];
  const float* b1   = (const float*)d_in[7];
  const float* Wl2  = (const float*)d_in[8];
  const float* Wr2  = (const float*)d_in[9];
  const float* We2  = (const float*)d_in[10];
  const float* att2 = (const float*)d_in[11];
  const float* b2   = (const float*)d_in[12];
  float* out = (float*)d_out;

  char* wsb = (char*)d_ws;
  size_t off = 0;
  auto alloc = [&](size_t bytes) {
    char* p = wsb + off;
    off += (bytes + 255) & ~(size_t)255;
    return p;
  };
  int* counts    = (int*)alloc((size_t)NN * 4);
  int* row_ptr   = (int*)alloc((size_t)(NN + 1) * 4);
  int* cursor    = (int*)alloc((size_t)NN * 4);
  int* perm      = (int*)alloc((size_t)NE * 4);
  float* xl1     = (float*)alloc((size_t)NN * 256 * 4);
  float* reg2    = (float*)alloc((size_t)NN * 256 * 4);  // xr1, later reused
  float* logits1 = (float*)alloc((size_t)NE * 4 * 4);
  float* hbuf    = (float*)alloc((size_t)NN * 256 * 4);
  float* xr1 = reg2;
  float* xl2 = reg2;                              // after layer-1 done, xr1 is dead
  float* xr2 = reg2 + (size_t)NN * 64;
  float* logits2 = reg2 + (size_t)NN * 128;

  // CSR by destination
  zero_i32<<<(NN + 255) / 256, 256, 0, stream>>>(counts, NN);
  count_dst<<<(NE + 255) / 256, 256, 0, stream>>>(ei, counts);
  scan_counts<<<1, 1024, 0, stream>>>(counts, row_ptr, cursor);
  scatter_edges<<<(NE + 255) / 256, 256, 0, stream>>>(ei, cursor, perm);

  // layer 1
  gemm_tile<128, 256, 16><<<NN / 16, 256, 0, stream>>>(x, Wl1, xl1, NN);
  gemm_tile<128, 256, 16><<<NN / 16, 256, 0, stream>>>(x, Wr1, xr1, NN);
  edge_logits1<<<NE / 4, 256, 0, stream>>>(ei, eatt, xl1, xr1, We1, att1, logits1);
  aggregate1<<<NN, 256, 0, stream>>>(ei, row_ptr, perm, logits1, xl1, b1, hbuf);

  // layer 2
  gemm_tile<256, 64, 16><<<NN / 16, 64, 0, stream>>>(hbuf, Wl2, xl2, NN);
  gemm_tile<256, 64, 16><<<NN / 16, 64, 0, stream>>>(hbuf, Wr2, xr2, NN);
  edge_logits2<<<NE / 4, 256, 0, stream>>>(ei, eatt, xl2, xr2, We2, att2, logits2);
  aggregate2<<<NN, 64, 0, stream>>>(ei, row_ptr, perm, logits2, xl2, b2, out);
}

// Round 3
// 570.556 us; speedup vs baseline: 1.3927x; 1.3927x over previous
//
#include <hip/hip_runtime.h>

#define NN 20000
#define NE 320000

// ---------------- CSR construction ----------------

__global__ void zero_i32(int* __restrict__ p, int n) {
  int i = blockIdx.x * blockDim.x + threadIdx.x;
  if (i < n) p[i] = 0;
}

__global__ void count_dst(const int* __restrict__ ei, int* __restrict__ counts) {
  int e = blockIdx.x * blockDim.x + threadIdx.x;
  if (e < NE) atomicAdd(&counts[ei[NE + e]], 1);
}

// single workgroup scan: row_ptr[i+1] = inclusive(counts), cursor[i] = exclusive
__global__ void scan_counts(const int* __restrict__ counts, int* __restrict__ row_ptr,
                            int* __restrict__ cursor) {
  __shared__ int sh[1024];
  __shared__ int carry;
  int t = threadIdx.x;
  if (t == 0) { carry = 0; row_ptr[0] = 0; }
  __syncthreads();
  for (int base = 0; base < NN; base += 1024) {
    int i = base + t;
    int v = (i < NN) ? counts[i] : 0;
    sh[t] = v;
    __syncthreads();
    for (int off = 1; off < 1024; off <<= 1) {
      int add = (t >= off) ? sh[t - off] : 0;
      __syncthreads();
      sh[t] += add;
      __syncthreads();
    }
    int inc = sh[t] + carry;
    if (i < NN) { row_ptr[i + 1] = inc; cursor[i] = inc - v; }
    __syncthreads();
    if (t == 1023) carry = inc;
    __syncthreads();
  }
}

__global__ void scatter_edges(const int* __restrict__ ei, int* __restrict__ cursor,
                              int* __restrict__ perm) {
  int e = blockIdx.x * blockDim.x + threadIdx.x;
  if (e < NE) {
    int d = ei[NE + e];
    int pos = atomicAdd(&cursor[d], 1);
    perm[pos] = e;
  }
}

// ---------------- dual projection GEMM ----------------
// C1 = A @ W1, C2 = A @ W2.  A tile staged once in LDS.
// Block = NC*G threads; group g handles rows [g*TMG, (g+1)*TMG) of the tile.

template<int K, int NC, int TMG, int G>
__global__ void gemm_dual_g(const float* __restrict__ A, const float* __restrict__ W1,
                            const float* __restrict__ W2, float* __restrict__ C1,
                            float* __restrict__ C2) {
  constexpr int TM = TMG * G;
  __shared__ float As[TM * K];
  int t = threadIdx.x;
  int n = t & (NC - 1);
  int g = t / NC;
  int m0 = blockIdx.x * TM;
  const float4* A4 = (const float4*)(A + (size_t)m0 * K);
  float4* As4 = (float4*)As;
  for (int idx = t; idx < TM * K / 4; idx += NC * G) As4[idx] = A4[idx];
  __syncthreads();
  float acc1[TMG], acc2[TMG];
#pragma unroll
  for (int m = 0; m < TMG; ++m) { acc1[m] = 0.f; acc2[m] = 0.f; }
  for (int k = 0; k < K; ++k) {
    float w1 = W1[k * NC + n];
    float w2 = W2[k * NC + n];
#pragma unroll
    for (int m = 0; m < TMG; ++m) {
      float a = As[(g * TMG + m) * K + k];
      acc1[m] += a * w1;
      acc2[m] += a * w2;
    }
  }
#pragma unroll
  for (int m = 0; m < TMG; ++m) {
    size_t row = m0 + g * TMG + m;
    C1[row * NC + n] = acc1[m];
    C2[row * NC + n] = acc2[m];
  }
}

// ---------------- fused attention + aggregation (online softmax) ----------------

// layer 1: block per node; 256 threads; wave w == head w; lane == channel.
__global__ void attn_agg1(const int* __restrict__ ei, const int* __restrict__ row_ptr,
                          const int* __restrict__ perm, const float* __restrict__ eattr,
                          const float* __restrict__ xl, const float* __restrict__ xr,
                          const float* __restrict__ We, const float* __restrict__ att,
                          const float* __restrict__ bias, float* __restrict__ hout) {
  int n = blockIdx.x;
  int t = threadIdx.x;  // t = h*64 + c
  int beg = row_ptr[n], end = row_ptr[n + 1];
  float xr_d = xr[(size_t)n * 256 + t];
  float we[16];
#pragma unroll
  for (int k = 0; k < 16; ++k) we[k] = We[k * 256 + t];
  float at = att[t];
  float m = -1e30f, denom = 0.f, acc = 0.f;

  if (beg < end) {
    // prefetch edge 0
    int e = perm[beg];
    int src = ei[e];
    float xl_s = xl[(size_t)src * 256 + t];
    float4 ea0 = ((const float4*)(eattr + (size_t)e * 16))[0];
    float4 ea1 = ((const float4*)(eattr + (size_t)e * 16))[1];
    float4 ea2 = ((const float4*)(eattr + (size_t)e * 16))[2];
    float4 ea3 = ((const float4*)(eattr + (size_t)e * 16))[3];
    for (int i = beg; i < end; ++i) {
      // prefetch next edge while computing current
      float xl_nxt = 0.f;
      float4 na0, na1, na2, na3;
      if (i + 1 < end) {
        int en = perm[i + 1];
        int sn = ei[en];
        xl_nxt = xl[(size_t)sn * 256 + t];
        const float4* p = (const float4*)(eattr + (size_t)en * 16);
        na0 = p[0]; na1 = p[1]; na2 = p[2]; na3 = p[3];
      }
      float v = xl_s + xr_d;
      v += ea0.x * we[0] + ea0.y * we[1] + ea0.z * we[2] + ea0.w * we[3];
      v += ea1.x * we[4] + ea1.y * we[5] + ea1.z * we[6] + ea1.w * we[7];
      v += ea2.x * we[8] + ea2.y * we[9] + ea2.z * we[10] + ea2.w * we[11];
      v += ea3.x * we[12] + ea3.y * we[13] + ea3.z * we[14] + ea3.w * we[15];
      v = (v > 0.f) ? v : 0.2f * v;
      float s = at * v;
#pragma unroll
      for (int off = 32; off > 0; off >>= 1) s += __shfl_xor(s, off);
      float m_new = fmaxf(m, s);
      float f = __expf(m - m_new);
      float a = __expf(s - m_new);
      denom = denom * f + a;
      acc = acc * f + a * xl_s;
      m = m_new;
      xl_s = xl_nxt;
      ea0 = na0; ea1 = na1; ea2 = na2; ea3 = na3;
    }
  }
  float o = (end > beg) ? (acc / denom) : 0.f;
  o += bias[t];
  o = (o > 0.f) ? o : (__expf(o) - 1.f);  // ELU (alpha=1)
  hout[(size_t)n * 256 + t] = o;
}

// layer 2: wave per node (4 nodes per block); lane == channel; H=1.
__global__ void attn_agg2(const int* __restrict__ ei, const int* __restrict__ row_ptr,
                          const int* __restrict__ perm, const float* __restrict__ eattr,
                          const float* __restrict__ xl, const float* __restrict__ xr,
                          const float* __restrict__ We, const float* __restrict__ att,
                          const float* __restrict__ bias, float* __restrict__ out) {
  int w = threadIdx.x >> 6, lane = threadIdx.x & 63;
  int n = blockIdx.x * 4 + w;
  if (n >= NN) return;
  int beg = row_ptr[n], end = row_ptr[n + 1];
  float xr_d = xr[(size_t)n * 64 + lane];
  float we[16];
#pragma unroll
  for (int k = 0; k < 16; ++k) we[k] = We[k * 64 + lane];
  float at = att[lane];
  float m = -1e30f, denom = 0.f, acc = 0.f;

  if (beg < end) {
    int e = perm[beg];
    int src = ei[e];
    float xl_s = xl[(size_t)src * 64 + lane];
    float4 ea0 = ((const float4*)(eattr + (size_t)e * 16))[0];
    float4 ea1 = ((const float4*)(eattr + (size_t)e * 16))[1];
    float4 ea2 = ((const float4*)(eattr + (size_t)e * 16))[2];
    float4 ea3 = ((const float4*)(eattr + (size_t)e * 16))[3];
    for (int i = beg; i < end; ++i) {
      float xl_nxt = 0.f;
      float4 na0, na1, na2, na3;
      if (i + 1 < end) {
        int en = perm[i + 1];
        int sn = ei[en];
        xl_nxt = xl[(size_t)sn * 64 + lane];
        const float4* p = (const float4*)(eattr + (size_t)en * 16);
        na0 = p[0]; na1 = p[1]; na2 = p[2]; na3 = p[3];
      }
      float v = xl_s + xr_d;
      v += ea0.x * we[0] + ea0.y * we[1] + ea0.z * we[2] + ea0.w * we[3];
      v += ea1.x * we[4] + ea1.y * we[5] + ea1.z * we[6] + ea1.w * we[7];
      v += ea2.x * we[8] + ea2.y * we[9] + ea2.z * we[10] + ea2.w * we[11];
      v += ea3.x * we[12] + ea3.y * we[13] + ea3.z * we[14] + ea3.w * we[15];
      v = (v > 0.f) ? v : 0.2f * v;
      float s = at * v;
#pragma unroll
      for (int off = 32; off > 0; off >>= 1) s += __shfl_xor(s, off);
      float m_new = fmaxf(m, s);
      float f = __expf(m - m_new);
      float a = __expf(s - m_new);
      denom = denom * f + a;
      acc = acc * f + a * xl_s;
      m = m_new;
      xl_s = xl_nxt;
      ea0 = na0; ea1 = na1; ea2 = na2; ea3 = na3;
    }
  }
  float o = (end > beg) ? (acc / denom) : 0.f;
  o += bias[lane];
  out[(size_t)n * 64 + lane] = o;
}

// ---------------- launch ----------------

extern "C" void kernel_launch(void* const* d_in, const int* in_sizes, int n_in,
                              void* d_out, int out_size, void* d_ws, size_t ws_size,
                              hipStream_t stream) {
  const float* x    = (const float*)d_in[0];
  const int*   ei   = (const int*)  d_in[1];
  const float* eatt = (const float*)d_in[2];
  const float* Wl1  = (const float*)d_in[3];
  const float* Wr1  = (const float*)d_in[4];
  const float* We1  = (const float*)d_in[5];
  const float* att1 = (const float*)d_in[6];
  const float* b1   = (const float*)d_in[7];
  const float* Wl2  = (const float*)d_in[8];
  const float* Wr2  = (const float*)d_in[9];
  const float* We2  = (const float*)d_in[10];
  const float* att2 = (const float*)d_in[11];
  const float* b2   = (const float*)d_in[12];
  float* out = (float*)d_out;

  char* wsb = (char*)d_ws;
  size_t off = 0;
  auto alloc = [&](size_t bytes) {
    char* p = wsb + off;
    off += (bytes + 255) & ~(size_t)255;
    return p;
  };
  int* counts  = (int*)alloc((size_t)NN * 4);
  int* row_ptr = (int*)alloc((size_t)(NN + 1) * 4);
  int* cursor  = (int*)alloc((size_t)NN * 4);
  int* perm    = (int*)alloc((size_t)NE * 4);
  float* xl1   = (float*)alloc((size_t)NN * 256 * 4);
  float* reg2  = (float*)alloc((size_t)NN * 256 * 4);  // xr1; reused for xl2/xr2
  float* hbuf  = (float*)alloc((size_t)NN * 256 * 4);
  float* xr1 = reg2;
  float* xl2 = reg2;                       // xr1 dead after layer 1
  float* xr2 = reg2 + (size_t)NN * 64;

  // CSR by destination
  zero_i32<<<(NN + 255) / 256, 256, 0, stream>>>(counts, NN);
  count_dst<<<(NE + 255) / 256, 256, 0, stream>>>(ei, counts);
  scan_counts<<<1, 1024, 0, stream>>>(counts, row_ptr, cursor);
  scatter_edges<<<(NE + 255) / 256, 256, 0, stream>>>(ei, cursor, perm);

  // layer 1: projections (dual) + fused attention/aggregation
  gemm_dual_g<128, 256, 16, 1><<<NN / 16, 256, 0, stream>>>(x, Wl1, Wr1, xl1, xr1);
  attn_agg1<<<NN, 256, 0, stream>>>(ei, row_ptr, perm, eatt, xl1, xr1, We1, att1, b1, hbuf);

  // layer 2
  gemm_dual_g<256, 64, 8, 4><<<NN / 32, 256, 0, stream>>>(hbuf, Wl2, Wr2, xl2, xr2);
  attn_agg2<<<NN / 4, 256, 0, stream>>>(ei, row_ptr, perm, eatt, xl2, xr2, We2, att2, b2, out);
}

// Round 4
// 466.295 us; speedup vs baseline: 1.7041x; 1.2236x over previous
//
#include <hip/hip_runtime.h>

#define NN 20000
#define NE 320000

// ---------------- CSR construction ----------------

__global__ void zero_i32(int* __restrict__ p, int n) {
  int i = blockIdx.x * blockDim.x + threadIdx.x;
  if (i < n) p[i] = 0;
}

__global__ void count_dst(const int* __restrict__ ei, int* __restrict__ counts) {
  int e = blockIdx.x * blockDim.x + threadIdx.x;
  if (e < NE) atomicAdd(&counts[ei[NE + e]], 1);
}

// three-kernel scan: per-block inclusive scan -> tiny serial scan of block sums -> finish
__global__ void scan_local(const int* __restrict__ counts, int* __restrict__ tmp,
                           int* __restrict__ bsum) {
  __shared__ int sh[1024];
  int b = blockIdx.x, t = threadIdx.x, i = b * 1024 + t;
  int v = (i < NN) ? counts[i] : 0;
  sh[t] = v;
  __syncthreads();
  for (int off = 1; off < 1024; off <<= 1) {
    int add = (t >= off) ? sh[t - off] : 0;
    __syncthreads();
    sh[t] += add;
    __syncthreads();
  }
  if (i < NN) tmp[i] = sh[t];
  if (t == 1023) bsum[b] = sh[t];
}

__global__ void scan_bsum(int* __restrict__ bsum, int nb) {
  if (threadIdx.x == 0) {
    int run = 0;
    for (int j = 0; j < nb; ++j) { int v = bsum[j]; bsum[j] = run; run += v; }
  }
}

__global__ void scan_finish(const int* __restrict__ counts, const int* __restrict__ tmp,
                            const int* __restrict__ bsum, int* __restrict__ row_ptr,
                            int* __restrict__ cursor) {
  int i = blockIdx.x * 256 + threadIdx.x;
  if (i == 0) row_ptr[0] = 0;
  if (i < NN) {
    int incl = tmp[i] + bsum[i >> 10];
    row_ptr[i + 1] = incl;
    cursor[i] = incl - counts[i];
  }
}

__global__ void scatter_edges(const int* __restrict__ ei, int* __restrict__ cursor,
                              int* __restrict__ perm) {
  int e = blockIdx.x * blockDim.x + threadIdx.x;
  if (e < NE) {
    int d = ei[NE + e];
    int pos = atomicAdd(&cursor[d], 1);
    perm[pos] = e;
  }
}

// ---------------- dual projection GEMM (float4 LDS reads) ----------------

template<int K, int NC, int TMG, int G>
__global__ void gemm_dual_g(const float* __restrict__ A, const float* __restrict__ W1,
                            const float* __restrict__ W2, float* __restrict__ C1,
                            float* __restrict__ C2) {
  constexpr int TM = TMG * G;
  __shared__ float As[TM * K];
  int t = threadIdx.x;
  int n = t & (NC - 1);
  int g = t / NC;
  int m0 = blockIdx.x * TM;
  const float4* A4 = (const float4*)(A + (size_t)m0 * K);
  float4* As4 = (float4*)As;
  for (int idx = t; idx < TM * K / 4; idx += NC * G) As4[idx] = A4[idx];
  __syncthreads();
  float acc1[TMG], acc2[TMG];
#pragma unroll
  for (int m = 0; m < TMG; ++m) { acc1[m] = 0.f; acc2[m] = 0.f; }
  for (int k = 0; k < K; k += 4) {
    float w10 = W1[(k + 0) * NC + n], w11 = W1[(k + 1) * NC + n];
    float w12 = W1[(k + 2) * NC + n], w13 = W1[(k + 3) * NC + n];
    float w20 = W2[(k + 0) * NC + n], w21 = W2[(k + 1) * NC + n];
    float w22 = W2[(k + 2) * NC + n], w23 = W2[(k + 3) * NC + n];
#pragma unroll
    for (int m = 0; m < TMG; ++m) {
      float4 a = *(const float4*)&As[(g * TMG + m) * K + k];
      acc1[m] += a.x * w10 + a.y * w11 + a.z * w12 + a.w * w13;
      acc2[m] += a.x * w20 + a.y * w21 + a.z * w22 + a.w * w23;
    }
  }
#pragma unroll
  for (int m = 0; m < TMG; ++m) {
    size_t row = m0 + g * TMG + m;
    C1[row * NC + n] = acc1[m];
    C2[row * NC + n] = acc2[m];
  }
}

// ---------------- fused attention + aggregation ----------------
// layer 1: block per node, 4 waves. Within a wave: lane = (head h = lane>>4,
// channel group cb = (lane&15)*4). One wave covers all 4 heads x 64 ch per edge.
// Wave w processes edges beg+w, beg+w+4, ... ; states merged via LDS.

__global__ void attn_agg1(const int* __restrict__ ei, const int* __restrict__ row_ptr,
                          const int* __restrict__ perm, const float* __restrict__ eattr,
                          const float* __restrict__ xl, const float* __restrict__ xr,
                          const float* __restrict__ We, const float* __restrict__ att,
                          const float* __restrict__ bias, float* __restrict__ hout) {
  int n = blockIdx.x;
  int t = threadIdx.x, w = t >> 6, lane = t & 63;
  int col = (lane >> 4) * 64 + (lane & 15) * 4;  // channel column in [0,256)
  float4 we[16];
#pragma unroll
  for (int k = 0; k < 16; ++k) we[k] = *(const float4*)(We + k * 256 + col);
  float4 at = *(const float4*)(att + col);
  float4 xr4 = *(const float4*)(xr + (size_t)n * 256 + col);
  int beg = row_ptr[n], end = row_ptr[n + 1];

  float m = -1e30f, denom = 0.f;
  float4 acc = make_float4(0.f, 0.f, 0.f, 0.f);

  for (int i = beg + w; i < end; i += 4) {
    int e = perm[i];
    int src = ei[e];
    float4 xl4 = *(const float4*)(xl + (size_t)src * 256 + col);
    const float4* ep = (const float4*)(eattr + (size_t)e * 16);
    float4 ea0 = ep[0], ea1 = ep[1], ea2 = ep[2], ea3 = ep[3];
    float eav[16] = {ea0.x, ea0.y, ea0.z, ea0.w, ea1.x, ea1.y, ea1.z, ea1.w,
                     ea2.x, ea2.y, ea2.z, ea2.w, ea3.x, ea3.y, ea3.z, ea3.w};
    float4 v;
    v.x = xl4.x + xr4.x; v.y = xl4.y + xr4.y;
    v.z = xl4.z + xr4.z; v.w = xl4.w + xr4.w;
#pragma unroll
    for (int k = 0; k < 16; ++k) {
      v.x += eav[k] * we[k].x; v.y += eav[k] * we[k].y;
      v.z += eav[k] * we[k].z; v.w += eav[k] * we[k].w;
    }
    v.x = (v.x > 0.f) ? v.x : 0.2f * v.x;
    v.y = (v.y > 0.f) ? v.y : 0.2f * v.y;
    v.z = (v.z > 0.f) ? v.z : 0.2f * v.z;
    v.w = (v.w > 0.f) ? v.w : 0.2f * v.w;
    float s = at.x * v.x + at.y * v.y + at.z * v.z + at.w * v.w;
#pragma unroll
    for (int off = 8; off >= 1; off >>= 1) s += __shfl_xor(s, off);  // 16-lane group
    float m_new = fmaxf(m, s);
    float f = __expf(m - m_new);
    float a = __expf(s - m_new);
    denom = denom * f + a;
    acc.x = acc.x * f + a * xl4.x; acc.y = acc.y * f + a * xl4.y;
    acc.z = acc.z * f + a * xl4.z; acc.w = acc.w * f + a * xl4.w;
    m = m_new;
  }

  __shared__ float sm[4][64], sd[4][64];
  __shared__ float4 sa[4][64];
  sm[w][lane] = m; sd[w][lane] = denom; sa[w][lane] = acc;
  __syncthreads();
  if (w == 0) {
    float M = sm[0][lane];
#pragma unroll
    for (int j = 1; j < 4; ++j) M = fmaxf(M, sm[j][lane]);
    float D = 0.f;
    float4 A = make_float4(0.f, 0.f, 0.f, 0.f);
#pragma unroll
    for (int j = 0; j < 4; ++j) {
      float f = __expf(sm[j][lane] - M);
      D += sd[j][lane] * f;
      float4 aj = sa[j][lane];
      A.x += aj.x * f; A.y += aj.y * f; A.z += aj.z * f; A.w += aj.w * f;
    }
    bool has = (end > beg);
    float4 b4 = *(const float4*)(bias + col);
    float4 o;
    o.x = (has ? A.x / D : 0.f) + b4.x;
    o.y = (has ? A.y / D : 0.f) + b4.y;
    o.z = (has ? A.z / D : 0.f) + b4.z;
    o.w = (has ? A.w / D : 0.f) + b4.w;
    o.x = (o.x > 0.f) ? o.x : (__expf(o.x) - 1.f);
    o.y = (o.y > 0.f) ? o.y : (__expf(o.y) - 1.f);
    o.z = (o.z > 0.f) ? o.z : (__expf(o.z) - 1.f);
    o.w = (o.w > 0.f) ? o.w : (__expf(o.w) - 1.f);
    *(float4*)(hout + (size_t)n * 256 + col) = o;
  }
}

// layer 2: wave per node (4 nodes/block). 4 subgroups of 16 lanes; subgroup g
// processes edges beg+g, beg+g+4, ...; lane covers 4 channels (cb=(lane&15)*4).
// Subgroup states merged with shfl_xor(16), shfl_xor(32).

__global__ void attn_agg2(const int* __restrict__ ei, const int* __restrict__ row_ptr,
                          const int* __restrict__ perm, const float* __restrict__ eattr,
                          const float* __restrict__ xl, const float* __restrict__ xr,
                          const float* __restrict__ We, const float* __restrict__ att,
                          const float* __restrict__ bias, float* __restrict__ out) {
  int t = threadIdx.x, w = t >> 6, lane = t & 63;
  int n = blockIdx.x * 4 + w;
  int g = lane >> 4, cb = (lane & 15) * 4;
  float4 we[16];
#pragma unroll
  for (int k = 0; k < 16; ++k) we[k] = *(const float4*)(We + k * 64 + cb);
  float4 at = *(const float4*)(att + cb);
  float4 xr4 = *(const float4*)(xr + (size_t)n * 64 + cb);
  int beg = row_ptr[n], end = row_ptr[n + 1];

  float m = -1e30f, denom = 0.f;
  float4 acc = make_float4(0.f, 0.f, 0.f, 0.f);

  for (int i = beg + g; i < end; i += 4) {
    int e = perm[i];
    int src = ei[e];
    float4 xl4 = *(const float4*)(xl + (size_t)src * 64 + cb);
    const float4* ep = (const float4*)(eattr + (size_t)e * 16);
    float4 ea0 = ep[0], ea1 = ep[1], ea2 = ep[2], ea3 = ep[3];
    float eav[16] = {ea0.x, ea0.y, ea0.z, ea0.w, ea1.x, ea1.y, ea1.z, ea1.w,
                     ea2.x, ea2.y, ea2.z, ea2.w, ea3.x, ea3.y, ea3.z, ea3.w};
    float4 v;
    v.x = xl4.x + xr4.x; v.y = xl4.y + xr4.y;
    v.z = xl4.z + xr4.z; v.w = xl4.w + xr4.w;
#pragma unroll
    for (int k = 0; k < 16; ++k) {
      v.x += eav[k] * we[k].x; v.y += eav[k] * we[k].y;
      v.z += eav[k] * we[k].z; v.w += eav[k] * we[k].w;
    }
    v.x = (v.x > 0.f) ? v.x : 0.2f * v.x;
    v.y = (v.y > 0.f) ? v.y : 0.2f * v.y;
    v.z = (v.z > 0.f) ? v.z : 0.2f * v.z;
    v.w = (v.w > 0.f) ? v.w : 0.2f * v.w;
    float s = at.x * v.x + at.y * v.y + at.z * v.z + at.w * v.w;
#pragma unroll
    for (int off = 8; off >= 1; off >>= 1) s += __shfl_xor(s, off);
    float m_new = fmaxf(m, s);
    float f = __expf(m - m_new);
    float a = __expf(s - m_new);
    denom = denom * f + a;
    acc.x = acc.x * f + a * xl4.x; acc.y = acc.y * f + a * xl4.y;
    acc.z = acc.z * f + a * xl4.z; acc.w = acc.w * f + a * xl4.w;
    m = m_new;
  }

  // merge the 4 subgroup states (butterfly over lane bits 4,5)
#pragma unroll
  for (int off = 16; off <= 32; off <<= 1) {
    float mo = __shfl_xor(m, off);
    float dn = __shfl_xor(denom, off);
    float ax = __shfl_xor(acc.x, off), ay = __shfl_xor(acc.y, off);
    float az = __shfl_xor(acc.z, off), aw = __shfl_xor(acc.w, off);
    float M = fmaxf(m, mo);
    float f1 = __expf(m - M), f2 = __expf(mo - M);
    denom = denom * f1 + dn * f2;
    acc.x = acc.x * f1 + ax * f2; acc.y = acc.y * f1 + ay * f2;
    acc.z = acc.z * f1 + az * f2; acc.w = acc.w * f1 + aw * f2;
    m = M;
  }

  if (lane < 16) {
    bool has = (end > beg);
    float4 b4 = *(const float4*)(bias + cb);
    float4 o;
    o.x = (has ? acc.x / denom : 0.f) + b4.x;
    o.y = (has ? acc.y / denom : 0.f) + b4.y;
    o.z = (has ? acc.z / denom : 0.f) + b4.z;
    o.w = (has ? acc.w / denom : 0.f) + b4.w;
    *(float4*)(out + (size_t)n * 64 + cb) = o;
  }
}

// ---------------- launch ----------------

extern "C" void kernel_launch(void* const* d_in, const int* in_sizes, int n_in,
                              void* d_out, int out_size, void* d_ws, size_t ws_size,
                              hipStream_t stream) {
  const float* x    = (const float*)d_in[0];
  const int*   ei   = (const int*)  d_in[1];
  const float* eatt = (const float*)d_in[2];
  const float* Wl1  = (const float*)d_in[3];
  const float* Wr1  = (const float*)d_in[4];
  const float* We1  = (const float*)d_in[5];
  const float* att1 = (const float*)d_in[6];
  const float* b1   = (const float*)d_in[7];
  const float* Wl2  = (const float*)d_in[8];
  const float* Wr2  = (const float*)d_in[9];
  const float* We2  = (const float*)d_in[10];
  const float* att2 = (const float*)d_in[11];
  const float* b2   = (const float*)d_in[12];
  float* out = (float*)d_out;

  char* wsb = (char*)d_ws;
  size_t off = 0;
  auto alloc = [&](size_t bytes) {
    char* p = wsb + off;
    off += (bytes + 255) & ~(size_t)255;
    return p;
  };
  int* counts  = (int*)alloc((size_t)NN * 4);
  int* tmp     = (int*)alloc((size_t)NN * 4);
  int* bsum    = (int*)alloc(32 * 4);
  int* row_ptr = (int*)alloc((size_t)(NN + 1) * 4);
  int* cursor  = (int*)alloc((size_t)NN * 4);
  int* perm    = (int*)alloc((size_t)NE * 4);
  float* xl1   = (float*)alloc((size_t)NN * 256 * 4);
  float* reg2  = (float*)alloc((size_t)NN * 256 * 4);  // xr1; reused for xl2/xr2
  float* hbuf  = (float*)alloc((size_t)NN * 256 * 4);
  float* xr1 = reg2;
  float* xl2 = reg2;                       // xr1 dead after layer 1
  float* xr2 = reg2 + (size_t)NN * 64;

  // CSR by destination
  zero_i32<<<(NN + 255) / 256, 256, 0, stream>>>(counts, NN);
  count_dst<<<(NE + 255) / 256, 256, 0, stream>>>(ei, counts);
  scan_local<<<(NN + 1023) / 1024, 1024, 0, stream>>>(counts, tmp, bsum);
  scan_bsum<<<1, 64, 0, stream>>>(bsum, (NN + 1023) / 1024);
  scan_finish<<<(NN + 255) / 256, 256, 0, stream>>>(counts, tmp, bsum, row_ptr, cursor);
  scatter_edges<<<(NE + 255) / 256, 256, 0, stream>>>(ei, cursor, perm);

  // layer 1
  gemm_dual_g<128, 256, 16, 1><<<NN / 16, 256, 0, stream>>>(x, Wl1, Wr1, xl1, xr1);
  attn_agg1<<<NN, 256, 0, stream>>>(ei, row_ptr, perm, eatt, xl1, xr1, We1, att1, b1, hbuf);

  // layer 2
  gemm_dual_g<256, 64, 8, 4><<<NN / 32, 256, 0, stream>>>(hbuf, Wl2, Wr2, xl2, xr2);
  attn_agg2<<<NN / 4, 256, 0, stream>>>(ei, row_ptr, perm, eatt, xl2, xr2, We2, att2, b2, out);
}